// Round 15
// baseline (218.141 us; speedup 1.0000x reference)
//
#include <hip/hip_runtime.h>
#include <hip/hip_bf16.h>

// MultiHeadAttention: B=4, T=2048, D=512, H=8, K=64.
// Inputs fp32, output fp32, intermediates bf16. THREE kernels:
// [1] gemm1f: qk/vT = x @ w_qkv^T — fp32 operands converted during staging
//     (R10 structure + R13 XCD swizzle: the missing piece that killed R10)
// [2] attn_v6 (R14-proven, 50.6 µs)
// [3] gemm3_64: out = attn @ w_proj^T + b_proj, BM=64 -> 4 blocks/CU

typedef unsigned short u16;
typedef __attribute__((ext_vector_type(8))) __bf16 bf16x8;
typedef __attribute__((ext_vector_type(8))) unsigned short u16x8;
typedef __attribute__((ext_vector_type(4))) unsigned short u16x4;
typedef __attribute__((ext_vector_type(4))) float f32x4;
typedef __attribute__((ext_vector_type(4))) unsigned u32x4;
typedef __attribute__((ext_vector_type(2))) unsigned u32x2;

#define DEV static __device__ __forceinline__

DEV void async16(const u16* g, u16* l) {  // global->LDS DMA, 16B/lane
  __builtin_amdgcn_global_load_lds(
      (const __attribute__((address_space(1))) unsigned int*)g,
      (__attribute__((address_space(3))) unsigned int*)l, 16, 0, 0);
}
DEV u16x8 gld8(const u16* p) { return *(const u16x8*)p; }
DEV void lst8(u16* p, u16x8 v) { *(u16x8*)p = v; }
DEV bf16x8 ldsld8(const u16* p) {
  return __builtin_bit_cast(bf16x8, *(const u16x8*)p);
}
DEV f32x4 mfma16(bf16x8 a, bf16x8 b, f32x4 c) {
  return __builtin_amdgcn_mfma_f32_16x16x32_bf16(a, b, c, 0, 0, 0);
}
DEV u16 f2b(float f) {  // fp32 -> bf16 RNE (epilogue-only)
  unsigned u = __builtin_bit_cast(unsigned, f);
  u += 0x7FFFu + ((u >> 16) & 1u);
  return (u16)(u >> 16);
}
DEV unsigned pk2(float x, float y) {  // v_cvt_pk_bf16_f32: low=x, high=y
  __hip_bfloat162 t = __float22bfloat162_rn(float2{x, y});
  unsigned r;
  __builtin_memcpy(&r, &t, 4);
  return r;
}
DEV u16x8 pack8(f32x4 a, f32x4 b) {
  u32x4 t;
  t[0] = pk2(a[0], a[1]);
  t[1] = pk2(a[2], a[3]);
  t[2] = pk2(b[0], b[1]);
  t[3] = pk2(b[2], b[3]);
  return __builtin_bit_cast(u16x8, t);
}

// ---------------------------------------------------------------------------
// gemm1f: qkv projection with fused fp32->bf16 conversion.
// A = x[8192,512] fp32, Bt = w_qkv[1536,512] fp32.
// BM=BN=128, BK=64 (two 32-halves), reg-prefetch + pack both operands.
// Grid 768 linear, XCD-swizzled: rt=(i&7)|(((i>>3)&7)<<3), ct=i>>6 — all 12
// col-tiles of a row-tile share i%8 (same XCD L2) -> A fetched ~once/row-tile.
// Output: cols<1024 -> qk (q pre-scaled by 0.125*log2e); cols>=1024 -> vT
// (transposed, pk2-packed 8B stores).
// ---------------------------------------------------------------------------
__global__ void gemm1f(const float* __restrict__ A, const float* __restrict__ Bt,
                       u16* __restrict__ qk, u16* __restrict__ vT, int K) {
  __shared__ __align__(16) u16 As[2][128 * 32];
  __shared__ __align__(16) u16 Bs[2][128 * 32];

  const int t = threadIdx.x, lane = t & 63, w = t >> 6;
  const int lane15 = lane & 15, quad = lane >> 4;
  const int wr = w >> 1, wc = w & 1;

  const int i = blockIdx.x;
  const int rt = (i & 7) | (((i >> 3) & 7) << 3);  // 0..63
  const int ct = i >> 6;                           // 0..11
  const long row0 = (long)rt * 128;
  const int col0 = ct * 128;

  const int sr = t >> 2, sc = (t & 3) * 8;
  const float* Ag = A + (row0 + sr) * (long)K + sc;
  const float* Bg = Bt + (long)(col0 + sr) * K + sc;
  u16* AsD[2][2];
  u16* BsD[2][2];
#pragma unroll
  for (int r = 0; r < 2; r++)
#pragma unroll
    for (int hf = 0; hf < 2; hf++) {
      AsD[r][hf] = &As[hf][(sr + r * 64) * 32 + sc];
      BsD[r][hf] = &Bs[hf][(sr + r * 64) * 32 + sc];
    }

  f32x4 acc[4][4];
#pragma unroll
  for (int ii = 0; ii < 4; ii++)
#pragma unroll
    for (int j = 0; j < 4; j++) acc[ii][j] = (f32x4)(0.0f);

  // prefetch k-chunk 0, packed to bf16 in regs
  u16x8 ra[2][2], rb[2][2];
#pragma unroll
  for (int r = 0; r < 2; r++)
#pragma unroll
    for (int hf = 0; hf < 2; hf++) {
      const float* pa = Ag + (long)r * 64 * K + hf * 32;
      const float* pb = Bg + (long)r * 64 * K + hf * 32;
      ra[r][hf] = pack8(*(const f32x4*)pa, *(const f32x4*)(pa + 4));
      rb[r][hf] = pack8(*(const f32x4*)pb, *(const f32x4*)(pb + 4));
    }

  for (int k0 = 0; k0 < K; k0 += 64) {
    __syncthreads();  // previous compute's LDS reads complete
#pragma unroll
    for (int r = 0; r < 2; r++)
#pragma unroll
      for (int hf = 0; hf < 2; hf++) {
        lst8(AsD[r][hf], ra[r][hf]);
        lst8(BsD[r][hf], rb[r][hf]);
      }
    __syncthreads();  // tiles visible

    {  // prefetch next k-chunk under compute (clamped)
      const int kp = (k0 + 64 < K) ? k0 + 64 : k0;
#pragma unroll
      for (int r = 0; r < 2; r++)
#pragma unroll
        for (int hf = 0; hf < 2; hf++) {
          const float* pa = Ag + (long)r * 64 * K + kp + hf * 32;
          const float* pb = Bg + (long)r * 64 * K + kp + hf * 32;
          ra[r][hf] = pack8(*(const f32x4*)pa, *(const f32x4*)(pa + 4));
          rb[r][hf] = pack8(*(const f32x4*)pb, *(const f32x4*)(pb + 4));
        }
    }

#pragma unroll
    for (int hf = 0; hf < 2; hf++) {
      bf16x8 a[4], b[4];
#pragma unroll
      for (int ii = 0; ii < 4; ii++)
        a[ii] = ldsld8(&As[hf][(wr * 64 + ii * 16 + lane15) * 32 + quad * 8]);
#pragma unroll
      for (int j = 0; j < 4; j++)
        b[j] = ldsld8(&Bs[hf][(wc * 64 + j * 16 + lane15) * 32 + quad * 8]);
#pragma unroll
      for (int ii = 0; ii < 4; ii++)
#pragma unroll
        for (int j = 0; j < 4; j++) acc[ii][j] = mfma16(a[ii], b[j], acc[ii][j]);
    }
  }

  if (col0 >= 1024) {
    // V part -> transposed: vT[(b*512+hd)*2048 + s], 4 s-consecutive per store
#pragma unroll
    for (int ii = 0; ii < 4; ii++)
#pragma unroll
      for (int j = 0; j < 4; j++) {
        const int hd = col0 - 1024 + wc * 64 + j * 16 + lane15;
        const long row = row0 + wr * 64 + ii * 16 + quad * 4;
        const long bb = row >> 11;
        const int s = (int)(row & 2047);
        u32x2 pr;
        pr[0] = pk2(acc[ii][j][0], acc[ii][j][1]);
        pr[1] = pk2(acc[ii][j][2], acc[ii][j][3]);
        *(u16x4*)(vT + (bb * 512 + hd) * 2048 + s) =
            __builtin_bit_cast(u16x4, pr);
      }
  } else {
    // Q/K part -> qk (LD=1024); q cols pre-scaled for attn's exp2
#pragma unroll
    for (int ii = 0; ii < 4; ii++)
#pragma unroll
      for (int j = 0; j < 4; j++) {
        const int col = col0 + wc * 64 + j * 16 + lane15;
        const float sc2 = (col < 512) ? 0.18033688f : 1.0f;
#pragma unroll
        for (int r = 0; r < 4; r++) {
          const long row = row0 + wr * 64 + ii * 16 + quad * 4 + r;
          qk[row * 1024 + col] = f2b(acc[ii][j][r] * sc2);
        }
      }
  }
}

// ---------------------------------------------------------------------------
// gemm3_64: C[M,512](fp32) = A[M,512](bf16) @ Bt[512,512](fp32)^T + bias.
// BM=64, BN=64, BK=64 -> 1024 blocks = 4/CU. 4 waves 2x2, wave tile 32x32.
// XCD-swizzled: rt=(i&7)|(((i>>3)&15)<<3) in [0,128), ct=i>>7 in [0,8).
// ---------------------------------------------------------------------------
__global__ void gemm3_64(const u16* __restrict__ A, const float* __restrict__ Bt,
                         const float* __restrict__ bias, float* __restrict__ C,
                         int N, int K) {
  __shared__ __align__(16) u16 As[2][64 * 32];
  __shared__ __align__(16) u16 Bs[2][64 * 32];

  const int t = threadIdx.x, lane = t & 63, w = t >> 6;
  const int lane15 = lane & 15, quad = lane >> 4;
  const int wr = w >> 1, wc = w & 1;

  const int i = blockIdx.x;
  const int rt = (i & 7) | (((i >> 3) & 15) << 3);  // 0..127
  const int ct = i >> 7;                            // 0..7
  const long row0 = (long)rt * 64;
  const int col0 = ct * 64;

  // A staging: wave w covers rows w*16..+16 (one async16 per half)
  const u16* Ag = A + (row0 + w * 16 + (lane >> 2)) * (long)K + (lane & 3) * 8;

  // B staging: thread t covers row t>>2 (0..63), fp32 cols (t&3)*16..+16
  const int brow = t >> 2, bc = (t & 3) * 16;
  const float* Bg = Bt + (long)(col0 + brow) * K + bc;
  u16* BsD = &Bs[bc >> 5][brow * 32 + (bc & 31)];

  f32x4 acc[2][2];
#pragma unroll
  for (int ii = 0; ii < 2; ii++)
#pragma unroll
    for (int j = 0; j < 2; j++) acc[ii][j] = (f32x4)(0.0f);

  f32x4 q0 = *(const f32x4*)Bg, q1 = *(const f32x4*)(Bg + 4);
  f32x4 q2 = *(const f32x4*)(Bg + 8), q3 = *(const f32x4*)(Bg + 12);

  for (int k0 = 0; k0 < K; k0 += 64) {
    __syncthreads();
#pragma unroll
    for (int hf = 0; hf < 2; hf++)
      async16(Ag + k0 + hf * 32, &As[hf][(w * 16) * 32]);
    lst8(BsD, pack8(q0, q1));
    lst8(BsD + 8, pack8(q2, q3));
    __syncthreads();

    {
      const int kp = (k0 + 64 < K) ? k0 + 64 : k0;
      q0 = *(const f32x4*)(Bg + kp);     q1 = *(const f32x4*)(Bg + kp + 4);
      q2 = *(const f32x4*)(Bg + kp + 8); q3 = *(const f32x4*)(Bg + kp + 12);
    }

#pragma unroll
    for (int hf = 0; hf < 2; hf++) {
      bf16x8 a[2], b[2];
#pragma unroll
      for (int ii = 0; ii < 2; ii++)
        a[ii] = ldsld8(&As[hf][(wr * 32 + ii * 16 + lane15) * 32 + quad * 8]);
#pragma unroll
      for (int j = 0; j < 2; j++)
        b[j] = ldsld8(&Bs[hf][(wc * 32 + j * 16 + lane15) * 32 + quad * 8]);
#pragma unroll
      for (int ii = 0; ii < 2; ii++)
#pragma unroll
        for (int j = 0; j < 2; j++) acc[ii][j] = mfma16(a[ii], b[j], acc[ii][j]);
    }
  }

#pragma unroll
  for (int ii = 0; ii < 2; ii++)
#pragma unroll
    for (int j = 0; j < 2; j++) {
      const int col = col0 + wc * 32 + j * 16 + lane15;
      const float bv = bias[col];
#pragma unroll
      for (int r = 0; r < 4; r++) {
        const long row = row0 + wr * 32 + ii * 16 + quad * 4 + r;
        C[row * (long)N + col] = acc[ii][j][r] + bv;
      }
    }
}

// ---------------------------------------------------------------------------
// attn_v6 (R14-proven, 50.6 µs): K from qk (LD=1024), V^T from vT; both
// b128-staged into pad-72 LDS; pk2-packed P-store; exp2 direct.
// ---------------------------------------------------------------------------
__global__ void attn_v6(const u16* __restrict__ qk, const u16* __restrict__ vT,
                        u16* __restrict__ out) {
  constexpr int T = 2048, LDQ = 1024;
  __shared__ __align__(16) u16 Ks[64 * 72];
  __shared__ __align__(16) u16 Vs[64 * 72];
  __shared__ __align__(16) u16 Ps[4][16 * 72];

  const int t = threadIdx.x, lane = t & 63, w = t >> 6;
  const int lane15 = lane & 15, quad = lane >> 4;

  const int i = blockIdx.x;
  int qb = i & 31;
  if (i >= 512) qb = 31 - qb;  // load-balance
  const int h = (i >> 5) & 7;
  const int b = (i >> 8) & 3;
  const long baseq = (long)b * T * LDQ;
  const u16* vTb = vT + ((long)b * 512 + h * 64) * 2048;

  const u16* gq =
      qk + baseq + (long)(qb * 64 + w * 16 + lane15) * LDQ + h * 64 + quad * 8;
  const bf16x8 qa0 = __builtin_bit_cast(bf16x8, *(const u16x8*)gq);
  const bf16x8 qa1 = __builtin_bit_cast(bf16x8, *(const u16x8*)(gq + 32));

  const int srow = t >> 3, sc8 = (t & 7) * 8;

  const int nsb = qb + 1;

  u16x8 kr0, kr1, vr0, vr1;
  {
    const u16* gk = qk + baseq + (long)srow * LDQ + 512 + h * 64 + sc8;
    kr0 = gld8(gk); kr1 = gld8(gk + (long)32 * LDQ);
    const u16* gv = vTb + (long)srow * 2048 + sc8;
    vr0 = gld8(gv); vr1 = gld8(gv + (long)32 * 2048);
  }

  float lp[4] = {0.0f, 0.0f, 0.0f, 0.0f};
  f32x4 o[4];
#pragma unroll
  for (int j = 0; j < 4; j++) o[j] = (f32x4)(0.0f);

  const int qrow_base = qb * 64 + w * 16 + quad * 4;

  for (int sb = 0; sb < nsb; ++sb) {
    __syncthreads();
    lst8(&Ks[srow * 72 + sc8], kr0);
    lst8(&Ks[(srow + 32) * 72 + sc8], kr1);
    lst8(&Vs[srow * 72 + sc8], vr0);
    lst8(&Vs[(srow + 32) * 72 + sc8], vr1);
    __syncthreads();

    {
      const int sp = (sb + 1 < nsb) ? sb + 1 : sb;
      const u16* gk =
          qk + baseq + (long)(sp * 64 + srow) * LDQ + 512 + h * 64 + sc8;
      kr0 = gld8(gk); kr1 = gld8(gk + (long)32 * LDQ);
      const u16* gv = vTb + (long)srow * 2048 + sp * 64 + sc8;
      vr0 = gld8(gv); vr1 = gld8(gv + (long)32 * 2048);
    }

    f32x4 sf[4];
#pragma unroll
    for (int j = 0; j < 4; j++) {
      f32x4 z = (f32x4)(0.0f);
      z = mfma16(qa0, ldsld8(&Ks[(j * 16 + lane15) * 72 + quad * 8]), z);
      sf[j] = mfma16(qa1, ldsld8(&Ks[(j * 16 + lane15) * 72 + quad * 8 + 32]), z);
    }

    if (sb == qb) {
      const int scol_base = sb * 64 + lane15;
#pragma unroll
      for (int j = 0; j < 4; j++)
#pragma unroll
        for (int r = 0; r < 4; r++) {
          float p = exp2f(sf[j][r]);
          if (scol_base + j * 16 > qrow_base + r) p = 0.0f;
          sf[j][r] = p;
          lp[r] += p;
        }
    } else {
#pragma unroll
      for (int j = 0; j < 4; j++)
#pragma unroll
        for (int r = 0; r < 4; r++) {
          const float p = exp2f(sf[j][r]);
          sf[j][r] = p;
          lp[r] += p;
        }
    }

    u16* myP = Ps[w];
#pragma unroll
    for (int r = 0; r < 4; r++) {
      const int ro = (quad * 4 + r) * 72 + lane15;
      const unsigned v01 = pk2(sf[0][r], sf[1][r]);
      const unsigned v23 = pk2(sf[2][r], sf[3][r]);
      myP[ro] = (u16)v01;
      myP[ro + 16] = (u16)(v01 >> 16);
      myP[ro + 32] = (u16)v23;
      myP[ro + 48] = (u16)(v23 >> 16);
    }
    __asm__ __volatile__("" ::: "memory");
    const bf16x8 pa0 = ldsld8(&myP[lane15 * 72 + quad * 8]);
    const bf16x8 pa1 = ldsld8(&myP[lane15 * 72 + quad * 8 + 32]);
    __asm__ __volatile__("" ::: "memory");

#pragma unroll
    for (int j = 0; j < 4; j++) {
      const int d0 = (j * 16 + lane15) * 72;
      o[j] = mfma16(pa0, ldsld8(&Vs[d0 + quad * 8]), o[j]);
      o[j] = mfma16(pa1, ldsld8(&Vs[d0 + quad * 8 + 32]), o[j]);
    }
  }

#pragma unroll
  for (int off = 1; off < 16; off <<= 1)
#pragma unroll
    for (int r = 0; r < 4; r++) lp[r] += __shfl_xor(lp[r], off);

  const long orow0 = (long)b * T + qb * 64 + w * 16;
  float inv[4];
#pragma unroll
  for (int r = 0; r < 4; r++) inv[r] = 1.0f / lp[r];
#pragma unroll
  for (int j = 0; j < 4; j++)
#pragma unroll
    for (int r = 0; r < 4; r++)
      out[(orow0 + quad * 4 + r) * 512 + h * 64 + j * 16 + lane15] =
          f2b(o[j][r] * inv[r]);
}

// ---------------------------------------------------------------------------
extern "C" void kernel_launch(void* const* d_in, const int* in_sizes, int n_in,
                              void* d_out, int out_size, void* d_ws, size_t ws_size,
                              hipStream_t stream) {
  const float* x      = (const float*)d_in[0];  // [4,2048,512] fp32
  const float* w_qkv  = (const float*)d_in[1];  // [1536,512]  fp32
  const float* w_proj = (const float*)d_in[2];  // [512,512]   fp32
  const float* b_proj = (const float*)d_in[3];  // [512]       fp32
  float* out = (float*)d_out;                   // [4,2048,512] fp32

  u16* qk = (u16*)d_ws;                   // [8192 x 1024] bf16 = 16 MiB
  u16* vT = qk + (size_t)8192 * 1024;     // [4 x 512 x 2048] bf16 = 8 MiB
  u16* xb = vT + (size_t)4 * 512 * 2048;  // [8192 x 512] bf16 = 8 MiB (attn out)

  // [1] qkv projection, fused fp32->bf16 (XCD-swizzled)
  gemm1f<<<768, 256, 0, stream>>>(x, w_qkv, qk, vT, 512);
  // [2] causal flash attention
  attn_v6<<<1024, 256, 0, stream>>>(qk, vT, xb);
  // [3] output projection + bias -> fp32 d_out (BM=64, 4 blocks/CU)
  gemm3_64<<<1024, 256, 0, stream>>>(xb, w_proj, b_proj, out, 512, 512);
}